// Round 13
// baseline (568.989 us; speedup 1.0000x reference)
//
#include <hip/hip_runtime.h>

#define IN_CH 1024
#define INTER 512
#define NEXP  128
#define TPE   512

typedef __bf16 bf16x8  __attribute__((ext_vector_type(8)));
typedef __bf16 bf16x4v __attribute__((ext_vector_type(4)));
typedef float  f32x4   __attribute__((ext_vector_type(4)));

// ISA-pinned staging load ("=&v" early-clobber: R8 abort lesson). Safe only
// where never spilled -> 1 blk/CU kernels (R9 NaN = spill under 128-cap).
#define GLOAD(dst, p) \
  asm volatile("global_load_dwordx4 %0, %1, off" : "=&v"(dst) : "v"(p))

// vmcnt wait + scheduler fence (rule #18: reg-only cvt hoists above inline
// asm waits despite "memory").
#define VM_WAIT() do { \
  asm volatile("s_waitcnt vmcnt(0)" ::: "memory"); \
  __builtin_amdgcn_sched_barrier(0); } while (0)

#define PHASE_SYNC() do { \
  __builtin_amdgcn_s_barrier(); \
  asm volatile("s_waitcnt lgkmcnt(0)" ::: "memory"); \
  __builtin_amdgcn_sched_barrier(0); \
  __builtin_amdgcn_s_setprio(1); } while (0)
#define PHASE_END() do { \
  __builtin_amdgcn_s_setprio(0); \
  __builtin_amdgcn_s_barrier(); } while (0)

// ---------------- Kernel A: h = silu(x@w1^T + b1) * (x@w3^T + b3) ------------
// R3/R12 geometry (BM=BN=128, BK=64, 8 waves 4x2, 96 KB dbuf, 1 blk/CU) +
// m201-style 4-phase K-step: each phase {ds_reads | one staging slice} ->
// bar -> lgkm0 -> 8-MFMA cluster -> bar. One vmcnt(0)/K-step at P0, waiting
// on loads in flight >=4 phases (counted-wait in effect, m218 lesson:
// drain-0-per-phase is what kills 4-phase, not the phases).
__global__ __launch_bounds__(512) void moe_h_kernel(
    const float* __restrict__ x, const int* __restrict__ idxs,
    const float* __restrict__ w1w, const float* __restrict__ w1b,
    const float* __restrict__ w3w, const float* __restrict__ w3b,
    __bf16* __restrict__ hbuf)
{
  __shared__ __align__(16) ushort sA [2][128*64];
  __shared__ __align__(16) ushort sB1[2][128*64];
  __shared__ __align__(16) ushort sB3[2][128*64];   // 96 KB

  // XCD swizzle: 2048 blocks, 256/XCD
  const int blk = (blockIdx.x & 7) * (NEXP*16/8) + (blockIdx.x >> 3);
  const int e   = blk >> 4;
  const int tl  = blk & 15;
  const int tm  = tl >> 2, tn = tl & 3;

  const int tid  = threadIdx.x;
  const int lane = tid & 63;
  const int wid  = tid >> 6;
  const int wm   = wid >> 1;       // 0..3 -> 32-row slice
  const int wn   = wid & 1;        // 0..1 -> 64-col slice

  const int r0 = tid >> 4;   // 0..31
  const int c4 = tid & 15;   // 0..15

  const float* aptr[4];
#pragma unroll
  for (int i = 0; i < 4; ++i) {
    const int tok = idxs[e*TPE + tm*128 + r0 + 32*i];
    aptr[i] = x + (size_t)tok*IN_CH + (c4<<2);
  }
  const float* b1p = w1w + ((size_t)e*INTER + tn*128 + r0)*IN_CH + (c4<<2);
  const float* b3p = w3w + ((size_t)e*INTER + tn*128 + r0)*IN_CH + (c4<<2);

  const int swz = ((((c4>>1) ^ (r0&7))<<3) | ((c4&1)<<2));

  f32x4 acc1[2][4], acc3[2][4];
#pragma unroll
  for (int a = 0; a < 2; ++a)
#pragma unroll
    for (int b = 0; b < 4; ++b) {
      acc1[a][b] = (f32x4){0.f,0.f,0.f,0.f};
      acc3[a][b] = (f32x4){0.f,0.f,0.f,0.f};
    }

  f32x4 xv[4], v1[4], v3[4];   // 48 staging VGPRs, asm-pinned

  // split load batches: H1 = xv[0..3] + v1[0..1]; H2 = v1[2..3] + v3[0..3]
  auto loadsH1 = [&](int kof) {
    GLOAD(xv[0], aptr[0] + kof);
    GLOAD(xv[1], aptr[1] + kof);
    GLOAD(xv[2], aptr[2] + kof);
    GLOAD(xv[3], aptr[3] + kof);
    GLOAD(v1[0], b1p + kof);
    GLOAD(v1[1], b1p + (size_t)32*IN_CH + kof);
  };
  auto loadsH2 = [&](int kof) {
    GLOAD(v1[2], b1p + (size_t)64*IN_CH + kof);
    GLOAD(v1[3], b1p + (size_t)96*IN_CH + kof);
    GLOAD(v3[0], b3p + kof);
    GLOAD(v3[1], b3p + (size_t)32*IN_CH + kof);
    GLOAD(v3[2], b3p + (size_t)64*IN_CH + kof);
    GLOAD(v3[3], b3p + (size_t)96*IN_CH + kof);
  };
  auto cvt4 = [](const f32x4& v) {
    bf16x4v b;
    b[0]=(__bf16)v[0]; b[1]=(__bf16)v[1]; b[2]=(__bf16)v[2]; b[3]=(__bf16)v[3];
    return b;
  };
  auto storeA = [&](int buf) {
#pragma unroll
    for (int i = 0; i < 4; ++i)
      *(bf16x4v*)&sA[buf][(r0 + 32*i)*64 + swz] = cvt4(xv[i]);
  };
  auto storeB1 = [&](int buf) {
#pragma unroll
    for (int i = 0; i < 4; ++i)
      *(bf16x4v*)&sB1[buf][(r0 + 32*i)*64 + swz] = cvt4(v1[i]);
  };
  auto storeB3 = [&](int buf) {
#pragma unroll
    for (int i = 0; i < 4; ++i)
      *(bf16x4v*)&sB3[buf][(r0 + 32*i)*64 + swz] = cvt4(v3[i]);
  };
  auto rdA = [&](int buf, int ks, bf16x8 af[2]) {
    const int k8 = (ks<<2) + (lane>>4);
#pragma unroll
    for (int mi = 0; mi < 2; ++mi) {
      const int r = wm*32 + mi*16 + (lane&15);
      af[mi] = *(const bf16x8*)&sA[buf][r*64 + ((k8 ^ (r&7))<<3)];
    }
  };
  auto rdBh = [&](int buf, int ks, int nh, bf16x8 bq[2], bf16x8 bt[2]) {
    const int k8 = (ks<<2) + (lane>>4);
#pragma unroll
    for (int nl = 0; nl < 2; ++nl) {
      const int r   = wn*64 + (nh*2 + nl)*16 + (lane&15);
      const int off = r*64 + ((k8 ^ (r&7))<<3);
      bq[nl] = *(const bf16x8*)&sB1[buf][off];
      bt[nl] = *(const bf16x8*)&sB3[buf][off];
    }
  };

#define MFMA8(NH) \
  _Pragma("unroll") \
  for (int mi = 0; mi < 2; ++mi) \
    _Pragma("unroll") \
    for (int nl = 0; nl < 2; ++nl) { \
      acc1[mi][(NH)*2+nl] = __builtin_amdgcn_mfma_f32_16x16x32_bf16(af[mi], bq[nl], acc1[mi][(NH)*2+nl], 0, 0, 0); \
      acc3[mi][(NH)*2+nl] = __builtin_amdgcn_mfma_f32_16x16x32_bf16(af[mi], bt[nl], acc3[mi][(NH)*2+nl], 0, 0, 0); \
    }

  // prologue: tile0 staged to buf0; tile1 in flight
  loadsH1(0); loadsH2(0);
  VM_WAIT();
  storeA(0); storeB1(0); storeB3(0);
  loadsH1(64); loadsH2(64);
  asm volatile("s_waitcnt lgkmcnt(0)" ::: "memory");
  __builtin_amdgcn_s_barrier();

  int cur = 0;
  const int NT = IN_CH/64;
  for (int kt = 0; kt < NT; ++kt) {
    bf16x8 af[2], bq[2], bt[2];

    // P0: reads(ks0,nh0) | vmcnt + write sA,sB1 of t+1
    rdA(cur, 0, af);
    rdBh(cur, 0, 0, bq, bt);
    if (kt < NT - 1) { VM_WAIT(); storeA(cur ^ 1); storeB1(cur ^ 1); }
    PHASE_SYNC();
    MFMA8(0)
    PHASE_END();

    // P1: reads(ks0,nh1) | write sB3 of t+1 | issue loads t+2 half1
    rdBh(cur, 0, 1, bq, bt);
    if (kt < NT - 1) storeB3(cur ^ 1);
    if (kt < NT - 2) loadsH1((kt+2)*64);
    PHASE_SYNC();
    MFMA8(1)
    PHASE_END();

    // P2: reads(ks1,nh0) | issue loads t+2 half2
    rdA(cur, 1, af);
    rdBh(cur, 1, 0, bq, bt);
    if (kt < NT - 2) loadsH2((kt+2)*64);
    PHASE_SYNC();
    MFMA8(0)
    PHASE_END();

    // P3: reads(ks1,nh1)
    rdBh(cur, 1, 1, bq, bt);
    PHASE_SYNC();
    MFMA8(1)
    PHASE_END();

    cur ^= 1;
  }
#undef MFMA8

  // epilogue: bias + SwiGLU, store bf16 h tile
  const int rowbase = tm*128 + wm*32;
  const int colbase = tn*128 + wn*64;
#pragma unroll
  for (int ni = 0; ni < 4; ++ni) {
    const int fc = colbase + ni*16 + (lane&15);
    const float b1v = w1b[e*INTER + fc];
    const float b3v = w3b[e*INTER + fc];
#pragma unroll
    for (int mi = 0; mi < 2; ++mi) {
#pragma unroll
      for (int j = 0; j < 4; ++j) {
        const int rl = rowbase + mi*16 + ((lane>>4)<<2) + j;
        const float h1 = acc1[mi][ni][j] + b1v;
        const float h3 = acc3[mi][ni][j] + b3v;
        const float s  = h1 / (1.0f + __expf(-h1));
        hbuf[((size_t)e*TPE + rl)*INTER + fc] = (__bf16)(s * h3);
      }
    }
  }
}

// ---------------- Kernel B: out = h @ w2^T + b2, scattered via idxs ----------
// R12-verbatim (plain HIP, 2 blocks/CU, 2 phases/K-tile, ~137 us).
__global__ __launch_bounds__(512) void moe_out_kernel(
    const __bf16* __restrict__ hbuf, const float* __restrict__ w2w,
    const float* __restrict__ w2b, const int* __restrict__ idxs,
    float* __restrict__ out)
{
  __shared__ __align__(16) ushort sA[2][128*64];
  __shared__ __align__(16) ushort sB[2][128*64];

  const int blk = (blockIdx.x & 7) * (NEXP*32/8) + (blockIdx.x >> 3);
  const int e   = blk >> 5;
  const int tl  = blk & 31;
  const int tm  = tl >> 3, tn = tl & 7;

  const int tid  = threadIdx.x;
  const int lane = tid & 63;
  const int wid  = tid >> 6;
  const int wm   = wid >> 1;       // 0..3
  const int wn   = wid & 1;        // 0..1

  const int rA   = tid >> 3;          // 0..63
  const int c8   = tid & 7;           // 0..7
  const int swzA = ((c8 ^ (rA&7))<<3);
  const __bf16* ap = hbuf + ((size_t)e*TPE + tm*128 + rA)*INTER + (c8<<3);

  const int r0   = tid >> 4;          // 0..31
  const int c4   = tid & 15;
  const int swzB = ((((c4>>1) ^ (r0&7))<<3) | ((c4&1)<<2));
  const float* bp = w2w + ((size_t)e*IN_CH + tn*128 + r0)*INTER + (c4<<2);

  f32x4 acc[2][4];
#pragma unroll
  for (int a = 0; a < 2; ++a)
#pragma unroll
    for (int b = 0; b < 4; ++b) acc[a][b] = (f32x4){0.f,0.f,0.f,0.f};

  uint4  hv[2];
  float4 wv[4];

  auto loads = [&](int kof) {
#pragma unroll
    for (int i = 0; i < 2; ++i)
      hv[i] = *(const uint4*)(ap + (size_t)(64*i)*INTER + kof);
#pragma unroll
    for (int i = 0; i < 4; ++i)
      wv[i] = *(const float4*)(bp + (size_t)(32*i)*INTER + kof);
  };
  auto stores = [&](int buf) {
#pragma unroll
    for (int i = 0; i < 2; ++i)
      *(uint4*)&sA[buf][(rA + 64*i)*64 + swzA] = hv[i];
#pragma unroll
    for (int i = 0; i < 4; ++i) {
      bf16x4v b;
      b[0]=(__bf16)wv[i].x; b[1]=(__bf16)wv[i].y; b[2]=(__bf16)wv[i].z; b[3]=(__bf16)wv[i].w;
      *(bf16x4v*)&sB[buf][(r0 + 32*i)*64 + swzB] = b;
    }
  };
  auto rdA = [&](int buf, int ks, bf16x8 af[2]) {
    const int k8 = (ks<<2) + (lane>>4);
#pragma unroll
    for (int mi = 0; mi < 2; ++mi) {
      const int r = wm*32 + mi*16 + (lane&15);
      af[mi] = *(const bf16x8*)&sA[buf][r*64 + ((k8 ^ (r&7))<<3)];
    }
  };
  auto rdB = [&](int buf, int ks, bf16x8 bfr[4]) {
    const int k8 = (ks<<2) + (lane>>4);
#pragma unroll
    for (int ni = 0; ni < 4; ++ni) {
      const int r = wn*64 + ni*16 + (lane&15);
      bfr[ni] = *(const bf16x8*)&sB[buf][r*64 + ((k8 ^ (r&7))<<3)];
    }
  };

  loads(0);
  stores(0);
  loads(64);
  asm volatile("s_waitcnt lgkmcnt(0)" ::: "memory");
  __builtin_amdgcn_s_barrier();

  int cur = 0;
  const int NT = INTER/64;
  for (int kt = 0; kt < NT; ++kt) {
    bf16x8 af[2], bfr[4];

    rdA(cur, 0, af);
    rdB(cur, 0, bfr);
    if (kt < NT - 1) stores(cur ^ 1);
    PHASE_SYNC();
#pragma unroll
    for (int mi = 0; mi < 2; ++mi)
#pragma unroll
      for (int ni = 0; ni < 4; ++ni)
        acc[mi][ni] = __builtin_amdgcn_mfma_f32_16x16x32_bf16(af[mi], bfr[ni], acc[mi][ni], 0, 0, 0);
    PHASE_END();

    rdA(cur, 1, af);
    rdB(cur, 1, bfr);
    if (kt < NT - 2) loads((kt+2)*64);
    PHASE_SYNC();
#pragma unroll
    for (int mi = 0; mi < 2; ++mi)
#pragma unroll
      for (int ni = 0; ni < 4; ++ni)
        acc[mi][ni] = __builtin_amdgcn_mfma_f32_16x16x32_bf16(af[mi], bfr[ni], acc[mi][ni], 0, 0, 0);
    PHASE_END();

    cur ^= 1;
  }

  const int rowbase = tm*128 + wm*32;
  const int colbase = tn*128 + wn*64;
  float b2v[4];
#pragma unroll
  for (int ni = 0; ni < 4; ++ni)
    b2v[ni] = w2b[e*IN_CH + colbase + ni*16 + (lane&15)];
#pragma unroll
  for (int mi = 0; mi < 2; ++mi) {
#pragma unroll
    for (int j = 0; j < 4; ++j) {
      const int rl  = rowbase + mi*16 + ((lane>>4)<<2) + j;
      const int tok = idxs[e*TPE + rl];
      float* orow = out + (size_t)tok*IN_CH;
#pragma unroll
      for (int ni = 0; ni < 4; ++ni)
        orow[colbase + ni*16 + (lane&15)] = acc[mi][ni][j] + b2v[ni];
    }
  }
}

extern "C" void kernel_launch(void* const* d_in, const int* in_sizes, int n_in,
                              void* d_out, int out_size, void* d_ws, size_t ws_size,
                              hipStream_t stream) {
  const float* x    = (const float*)d_in[0];
  const int*   idxs = (const int*)d_in[1];
  const float* w1w  = (const float*)d_in[2];
  const float* w1b  = (const float*)d_in[3];
  const float* w2w  = (const float*)d_in[4];
  const float* w2b  = (const float*)d_in[5];
  const float* w3w  = (const float*)d_in[6];
  const float* w3b  = (const float*)d_in[7];
  float*  out  = (float*)d_out;
  __bf16* hbuf = (__bf16*)d_ws;   // 128*512*512 bf16 = 64 MB intermediate

  moe_h_kernel<<<dim3(NEXP*16), dim3(512), 0, stream>>>(x, idxs, w1w, w1b, w3w, w3b, hbuf);
  moe_out_kernel<<<dim3(NEXP*32), dim3(512), 0, stream>>>(hbuf, w2w, w2b, idxs, out);
}

// Round 14
// 528.066 us; speedup vs baseline: 1.0775x; 1.0775x over previous
//
#include <hip/hip_runtime.h>

#define IN_CH 1024
#define INTER 512
#define NEXP  128
#define TPE   512

typedef __bf16 bf16x8  __attribute__((ext_vector_type(8)));
typedef __bf16 bf16x4v __attribute__((ext_vector_type(4)));
typedef float  f32x4   __attribute__((ext_vector_type(4)));

// ISA-pinned staging load ("=&v" early-clobber: R8 abort lesson). Safe only
// where never spilled -> 1 blk/CU kernels with VGPR headroom (R9 NaN).
#define GLOAD(dst, p) \
  asm volatile("global_load_dwordx4 %0, %1, off" : "=&v"(dst) : "v"(p))

// vmcnt wait + scheduler fence (rule #18).
#define VM_WAIT() do { \
  asm volatile("s_waitcnt vmcnt(0)" ::: "memory"); \
  __builtin_amdgcn_sched_barrier(0); } while (0)

#define PHASE_SYNC() do { \
  __builtin_amdgcn_s_barrier(); \
  asm volatile("s_waitcnt lgkmcnt(0)" ::: "memory"); \
  __builtin_amdgcn_sched_barrier(0); \
  __builtin_amdgcn_s_setprio(1); } while (0)
#define PHASE_END() do { \
  __builtin_amdgcn_s_setprio(0); \
  __builtin_amdgcn_s_barrier(); } while (0)

// ---------------- Kernel A: h = silu(x@w1^T + b1) * (x@w3^T + b3) ------------
// NEW STRUCTURE: wave = 128 tok x 16 f of BOTH gemms (8 m-tiles, acc 64 VGPR).
// B (w1,w3) never touches LDS: per-lane fragment-layout global loads
// (row = lane&15 -> 16 rows x 64B contiguous), cvt in regs, reg-dbuf across
// K-steps. Only sA (x, bf16, swizzled) in LDS: 32 KB dbuf, ONE barrier/K-step.
__global__ __launch_bounds__(512) void moe_h_kernel(
    const float* __restrict__ x, const int* __restrict__ idxs,
    const float* __restrict__ w1w, const float* __restrict__ w1b,
    const float* __restrict__ w3w, const float* __restrict__ w3b,
    __bf16* __restrict__ hbuf)
{
  __shared__ __align__(16) ushort sA[2][128*64];   // 32 KB

  // XCD swizzle: 2048 blocks, 256/XCD
  const int blk = (blockIdx.x & 7) * (NEXP*16/8) + (blockIdx.x >> 3);
  const int e   = blk >> 4;
  const int tl  = blk & 15;
  const int tm  = tl >> 2, tn = tl & 3;     // tm: 128-token tile, tn: 128-f tile

  const int tid  = threadIdx.x;
  const int lane = tid & 63;
  const int w    = tid >> 6;                // 0..7 -> 16-col slice of tn-tile

  // A staging (R12-verbatim): thread (r0, c4) stages rows r0+32i
  const int r0 = tid >> 4;   // 0..31
  const int c4 = tid & 15;   // 0..15
  const int swz = ((((c4>>1) ^ (r0&7))<<3) | ((c4&1)<<2));

  const float* aptr[4];
#pragma unroll
  for (int i = 0; i < 4; ++i) {
    const int tok = idxs[e*TPE + tm*128 + r0 + 32*i];
    aptr[i] = x + (size_t)tok*IN_CH + (c4<<2);
  }

  // B per-lane fragment pointers: element (f = tn*128 + w*16 + (lane&15),
  // k = (lane>>4)*8). Loads at +kof+ks*32(+4) reproduce exactly the frag the
  // old sB read produced (verified mapping: row=lane&15, k=(lane>>4)*8+j).
  const size_t frow = (size_t)e*INTER + tn*128 + w*16 + (lane&15);
  const float* b1p = w1w + frow*IN_CH + ((lane>>4)<<3);
  const float* b3p = w3w + frow*IN_CH + ((lane>>4)<<3);

  f32x4 acc1[8], acc3[8];
#pragma unroll
  for (int a = 0; a < 8; ++a) {
    acc1[a] = (f32x4){0.f,0.f,0.f,0.f};
    acc3[a] = (f32x4){0.f,0.f,0.f,0.f};
  }

  f32x4 xv[4];                              // A staging (GLOAD-pinned)
  // B reg-dbuf: set q = even kt, set r = odd kt; [ks][half], static indexing
  f32x4 q1[2][2], q3[2][2], r1[2][2], r3[2][2];

  auto loadsA = [&](int kof) {
#pragma unroll
    for (int i = 0; i < 4; ++i) GLOAD(xv[i], aptr[i] + kof);
  };
  auto cvt4 = [](const f32x4& v) {
    bf16x4v b;
    b[0]=(__bf16)v[0]; b[1]=(__bf16)v[1]; b[2]=(__bf16)v[2]; b[3]=(__bf16)v[3];
    return b;
  };
  auto storeA = [&](int buf) {
#pragma unroll
    for (int i = 0; i < 4; ++i)
      *(bf16x4v*)&sA[buf][(r0 + 32*i)*64 + swz] = cvt4(xv[i]);
  };
  auto loadsB = [&](f32x4 bq[2][2], f32x4 bt[2][2], int kof) {
#pragma unroll
    for (int ks = 0; ks < 2; ++ks) {
      GLOAD(bq[ks][0], b1p + kof + ks*32);
      GLOAD(bq[ks][1], b1p + kof + ks*32 + 4);
      GLOAD(bt[ks][0], b3p + kof + ks*32);
      GLOAD(bt[ks][1], b3p + kof + ks*32 + 4);
    }
  };
  auto cvt8 = [](const f32x4& lo, const f32x4& hi) {
    bf16x8 r;
    r[0]=(__bf16)lo[0]; r[1]=(__bf16)lo[1]; r[2]=(__bf16)lo[2]; r[3]=(__bf16)lo[3];
    r[4]=(__bf16)hi[0]; r[5]=(__bf16)hi[1]; r[6]=(__bf16)hi[2]; r[7]=(__bf16)hi[3];
    return r;
  };

  const int NT = IN_CH/64;

  // one K-step: frags in CUR (landed after VM_WAIT), prefetch NXT
  auto kstep = [&](int kt, f32x4 cq[2][2], f32x4 ct[2][2],
                   f32x4 nq[2][2], f32x4 nt[2][2]) {
    const int cur = kt & 1;
    VM_WAIT();                              // B(t) + A(t+1) landed
    if (kt < NT - 1) storeA(cur ^ 1);       // stage x tile t+1
    if (kt < NT - 2) loadsA((kt+2)*64);     // x tile t+2 in flight
    if (kt < NT - 1) loadsB(nq, nt, (kt+1)*64);  // w tiles t+1 in flight
    // cvt B(t) to bf16 frags
    bf16x8 f1[2], f3[2];
#pragma unroll
    for (int ks = 0; ks < 2; ++ks) {
      f1[ks] = cvt8(cq[ks][0], cq[ks][1]);
      f3[ks] = cvt8(ct[ks][0], ct[ks][1]);
    }
    __builtin_amdgcn_s_setprio(1);
#pragma unroll
    for (int ks = 0; ks < 2; ++ks) {
      const int k8 = (ks<<2) + (lane>>4);
#pragma unroll
      for (int mi = 0; mi < 8; ++mi) {
        const int r = mi*16 + (lane&15);
        const bf16x8 af = *(const bf16x8*)&sA[cur][r*64 + ((k8 ^ (r&7))<<3)];
        acc1[mi] = __builtin_amdgcn_mfma_f32_16x16x32_bf16(af, f1[ks], acc1[mi], 0, 0, 0);
        acc3[mi] = __builtin_amdgcn_mfma_f32_16x16x32_bf16(af, f3[ks], acc3[mi], 0, 0, 0);
      }
    }
    __builtin_amdgcn_s_setprio(0);
    asm volatile("s_waitcnt lgkmcnt(0)" ::: "memory");
    __builtin_amdgcn_s_barrier();
  };

  // prologue: B(t0)+A(t0) in flight; stage A(t0); A(t1) in flight
  loadsB(q1, q3, 0);
  loadsA(0);
  VM_WAIT();
  storeA(0);
  loadsA(64);
  asm volatile("s_waitcnt lgkmcnt(0)" ::: "memory");
  __builtin_amdgcn_s_barrier();

  for (int k2 = 0; k2 < NT/2; ++k2) {
    kstep(2*k2,     q1, q3, r1, r3);
    kstep(2*k2 + 1, r1, r3, q1, q3);
  }

  // epilogue: bias + SwiGLU. Per lane: fixed f-col -> single bias pair.
  const int fc = tn*128 + w*16 + (lane&15);
  const float b1v = w1b[e*INTER + fc];
  const float b3v = w3b[e*INTER + fc];
  const int rowbase = tm*128;
#pragma unroll
  for (int mi = 0; mi < 8; ++mi) {
#pragma unroll
    for (int j = 0; j < 4; ++j) {
      const int rl = rowbase + mi*16 + ((lane>>4)<<2) + j;
      const float h1 = acc1[mi][j] + b1v;
      const float h3 = acc3[mi][j] + b3v;
      const float s  = h1 / (1.0f + __expf(-h1));
      hbuf[((size_t)e*TPE + rl)*INTER + fc] = (__bf16)(s * h3);
    }
  }
}

// ---------------- Kernel B: out = h @ w2^T + b2, scattered via idxs ----------
// R12-verbatim (plain HIP, 2 blocks/CU, 2 phases/K-tile).
__global__ __launch_bounds__(512) void moe_out_kernel(
    const __bf16* __restrict__ hbuf, const float* __restrict__ w2w,
    const float* __restrict__ w2b, const int* __restrict__ idxs,
    float* __restrict__ out)
{
  __shared__ __align__(16) ushort sA[2][128*64];
  __shared__ __align__(16) ushort sB[2][128*64];

  const int blk = (blockIdx.x & 7) * (NEXP*32/8) + (blockIdx.x >> 3);
  const int e   = blk >> 5;
  const int tl  = blk & 31;
  const int tm  = tl >> 3, tn = tl & 7;

  const int tid  = threadIdx.x;
  const int lane = tid & 63;
  const int wid  = tid >> 6;
  const int wm   = wid >> 1;       // 0..3
  const int wn   = wid & 1;        // 0..1

  const int rA   = tid >> 3;          // 0..63
  const int c8   = tid & 7;           // 0..7
  const int swzA = ((c8 ^ (rA&7))<<3);
  const __bf16* ap = hbuf + ((size_t)e*TPE + tm*128 + rA)*INTER + (c8<<3);

  const int r0   = tid >> 4;          // 0..31
  const int c4   = tid & 15;
  const int swzB = ((((c4>>1) ^ (r0&7))<<3) | ((c4&1)<<2));
  const float* bp = w2w + ((size_t)e*IN_CH + tn*128 + r0)*INTER + (c4<<2);

  f32x4 acc[2][4];
#pragma unroll
  for (int a = 0; a < 2; ++a)
#pragma unroll
    for (int b = 0; b < 4; ++b) acc[a][b] = (f32x4){0.f,0.f,0.f,0.f};

  uint4  hv[2];
  float4 wv[4];

  auto loads = [&](int kof) {
#pragma unroll
    for (int i = 0; i < 2; ++i)
      hv[i] = *(const uint4*)(ap + (size_t)(64*i)*INTER + kof);
#pragma unroll
    for (int i = 0; i < 4; ++i)
      wv[i] = *(const float4*)(bp + (size_t)(32*i)*INTER + kof);
  };
  auto stores = [&](int buf) {
#pragma unroll
    for (int i = 0; i < 2; ++i)
      *(uint4*)&sA[buf][(rA + 64*i)*64 + swzA] = hv[i];
#pragma unroll
    for (int i = 0; i < 4; ++i) {
      bf16x4v b;
      b[0]=(__bf16)wv[i].x; b[1]=(__bf16)wv[i].y; b[2]=(__bf16)wv[i].z; b[3]=(__bf16)wv[i].w;
      *(bf16x4v*)&sB[buf][(r0 + 32*i)*64 + swzB] = b;
    }
  };
  auto rdA = [&](int buf, int ks, bf16x8 af[2]) {
    const int k8 = (ks<<2) + (lane>>4);
#pragma unroll
    for (int mi = 0; mi < 2; ++mi) {
      const int r = wm*32 + mi*16 + (lane&15);
      af[mi] = *(const bf16x8*)&sA[buf][r*64 + ((k8 ^ (r&7))<<3)];
    }
  };
  auto rdB = [&](int buf, int ks, bf16x8 bfr[4]) {
    const int k8 = (ks<<2) + (lane>>4);
#pragma unroll
    for (int ni = 0; ni < 4; ++ni) {
      const int r = wn*64 + ni*16 + (lane&15);
      bfr[ni] = *(const bf16x8*)&sB[buf][r*64 + ((k8 ^ (r&7))<<3)];
    }
  };

  loads(0);
  stores(0);
  loads(64);
  asm volatile("s_waitcnt lgkmcnt(0)" ::: "memory");
  __builtin_amdgcn_s_barrier();

  int cur = 0;
  const int NT = INTER/64;
  for (int kt = 0; kt < NT; ++kt) {
    bf16x8 af[2], bfr[4];

    rdA(cur, 0, af);
    rdB(cur, 0, bfr);
    if (kt < NT - 1) stores(cur ^ 1);
    PHASE_SYNC();
#pragma unroll
    for (int mi = 0; mi < 2; ++mi)
#pragma unroll
      for (int ni = 0; ni < 4; ++ni)
        acc[mi][ni] = __builtin_amdgcn_mfma_f32_16x16x32_bf16(af[mi], bfr[ni], acc[mi][ni], 0, 0, 0);
    PHASE_END();

    rdA(cur, 1, af);
    rdB(cur, 1, bfr);
    if (kt < NT - 2) loads((kt+2)*64);
    PHASE_SYNC();
#pragma unroll
    for (int mi = 0; mi < 2; ++mi)
#pragma unroll
      for (int ni = 0; ni < 4; ++ni)
        acc[mi][ni] = __builtin_amdgcn_mfma_f32_16x16x32_bf16(af[mi], bfr[ni], acc[mi][ni], 0, 0, 0);
    PHASE_END();

    cur ^= 1;
  }

  const int rowbase = tm*128 + wm*32;
  const int colbase = tn*128 + wn*64;
  float b2v[4];
#pragma unroll
  for (int ni = 0; ni < 4; ++ni)
    b2v[ni] = w2b[e*IN_CH + colbase + ni*16 + (lane&15)];
#pragma unroll
  for (int mi = 0; mi < 2; ++mi) {
#pragma unroll
    for (int j = 0; j < 4; ++j) {
      const int rl  = rowbase + mi*16 + ((lane>>4)<<2) + j;
      const int tok = idxs[e*TPE + rl];
      float* orow = out + (size_t)tok*IN_CH;
#pragma unroll
      for (int ni = 0; ni < 4; ++ni)
        orow[colbase + ni*16 + (lane&15)] = acc[mi][ni][j] + b2v[ni];
    }
  }
}

extern "C" void kernel_launch(void* const* d_in, const int* in_sizes, int n_in,
                              void* d_out, int out_size, void* d_ws, size_t ws_size,
                              hipStream_t stream) {
  const float* x    = (const float*)d_in[0];
  const int*   idxs = (const int*)d_in[1];
  const float* w1w  = (const float*)d_in[2];
  const float* w1b  = (const float*)d_in[3];
  const float* w2w  = (const float*)d_in[4];
  const float* w2b  = (const float*)d_in[5];
  const float* w3w  = (const float*)d_in[6];
  const float* w3b  = (const float*)d_in[7];
  float*  out  = (float*)d_out;
  __bf16* hbuf = (__bf16*)d_ws;   // 128*512*512 bf16 = 64 MB intermediate

  moe_h_kernel<<<dim3(NEXP*16), dim3(512), 0, stream>>>(x, idxs, w1w, w1b, w3w, w3b, hbuf);
  moe_out_kernel<<<dim3(NEXP*32), dim3(512), 0, stream>>>(hbuf, w2w, w2b, idxs, out);
}